// Round 1
// baseline (402.970 us; speedup 1.0000x reference)
//
#include <hip/hip_runtime.h>
#include <stdint.h>

#define B_ 64
#define N_ 16
#define T_ 128
#define I_ 256
#define H_ 256
#define G_ 768   // 3*H
#define TC 64    // time chunk

typedef __attribute__((ext_vector_type(8))) short bf8;        // 8 bf16 in 4 VGPRs (MFMA frag)
typedef __attribute__((ext_vector_type(8))) unsigned short u16x8;
typedef __attribute__((ext_vector_type(4))) float f4;

static __device__ __forceinline__ unsigned short f2bf(float f) {
    uint32_t u = __builtin_bit_cast(uint32_t, f);
    u += 0x7fffu + ((u >> 16) & 1u);   // RNE
    return (unsigned short)(u >> 16);
}
static __device__ __forceinline__ float bf2f(unsigned short s) {
    return __builtin_bit_cast(float, ((uint32_t)s) << 16);
}

// ---- ws layout (bytes) ----
// wih_bf  : 16*768*256 ushort = 6291456
// whh_frag: 16*48*8*64*8 ushort = 6291456   (pre-shuffled into MFMA B-fragment order)
// bias_f  : 16*768 float = 49152            (bih + bhh for r/z cols, bih only for n cols)
// h32ws   : 64*16*256 float = 1048576       (carry h between T-chunks)
// IH      : 64*16*TC*768 ushort = 100663296 (one T-chunk of folded input projection, bf16)
#define OFF_WIH   0ull
#define OFF_WHH   6291456ull
#define OFF_BIAS  12582912ull
#define OFF_H32   12632064ull
#define OFF_IH    13680640ull
#define WS_NEEDED (OFF_IH + 100663296ull)

// ---------------- stage 0: convert/shuffle weights ----------------
__global__ __launch_bounds__(256) void prep_kernel(
        const float* __restrict__ wih, const float* __restrict__ whh,
        const float* __restrict__ bih, const float* __restrict__ bhh,
        unsigned char* ws) {
    unsigned short* wih_bf = (unsigned short*)(ws + OFF_WIH);
    unsigned short* whh_fr = (unsigned short*)(ws + OFF_WHH);
    float* bias_f = (float*)(ws + OFF_BIAS);
    int gid = blockIdx.x * blockDim.x + threadIdx.x;
    int nthr = gridDim.x * blockDim.x;

    // wih: straight convert (layout [n][g][k] kept), 8 elems/iter
    for (int o = gid; o < 393216; o += nthr) {
        const float* s = wih + (size_t)o * 8;
        u16x8 v;
        #pragma unroll
        for (int e = 0; e < 8; e++) v[e] = f2bf(s[e]);
        *(u16x8*)(wih_bf + (size_t)o * 8) = v;
    }
    // whh: gather into fragment order [n][ct(48)][kt(8)][lane(64)][e(8)]
    //   B-frag def: col = ct*16 + (lane&15), k = kt*32 + (lane>>4)*8 + e
    for (int o = gid; o < 393216; o += nthr) {
        int lane = o & 63, kt = (o >> 6) & 7, ct = (o >> 9) % 48, n = o / 24576;
        int gcol = ct * 16 + (lane & 15);
        int k0 = kt * 32 + (lane >> 4) * 8;
        const float* s = whh + ((size_t)(n * G_ + gcol)) * H_ + k0;
        u16x8 v;
        #pragma unroll
        for (int e = 0; e < 8; e++) v[e] = f2bf(s[e]);
        *(u16x8*)(whh_fr + (size_t)o * 8) = v;
    }
    // folded bias
    for (int o = gid; o < N_ * G_; o += nthr) {
        int g = o % G_;
        bias_f[o] = bih[o] + (g < 512 ? bhh[o] : 0.f);
    }
}

// ---------------- stage 1: IH = bf16( x @ wih^T + bias_f ) for one T-chunk ----------------
// grid: 1024 blocks = (n,b); block computes 64 t-rows x 768 cols, K=256
__global__ __launch_bounds__(512, 2) void ih_gemm(
        const float* __restrict__ x, const unsigned char* __restrict__ wsr,
        unsigned char* ws, int t0) {
    const unsigned short* wih_bf = (const unsigned short*)(wsr + OFF_WIH);
    const float* bias_f = (const float*)(wsr + OFF_BIAS);
    unsigned short* IH = (unsigned short*)(ws + OFF_IH);

    __shared__ __align__(16) unsigned short As[64 * 256];   // x tile, bf16, swizzled
    __shared__ __align__(16) unsigned short Bs[128 * 256];  // wih chunk, swizzled

    int tid = threadIdx.x;
    int lane = tid & 63, w = tid >> 6;
    int wr = w >> 2, wc = w & 3;             // wave grid 2 x 4: rows 32, cols 32
    int n = blockIdx.x >> 6, b = blockIdx.x & 63;

    // stage A: 64 rows x 256 k (fp32 -> bf16), 16B chunks
    {
        const float* xb = x + (((size_t)(b * N_ + n)) * T_ + t0) * I_;
        #pragma unroll
        for (int i = 0; i < 4; i++) {
            int chunk = i * 512 + tid;
            int row = chunk >> 5, c16 = chunk & 31;
            const float* s = xb + row * I_ + c16 * 8;
            float4 f0 = *(const float4*)s;
            float4 f1 = *(const float4*)(s + 4);
            u16x8 v;
            v[0] = f2bf(f0.x); v[1] = f2bf(f0.y); v[2] = f2bf(f0.z); v[3] = f2bf(f0.w);
            v[4] = f2bf(f1.x); v[5] = f2bf(f1.y); v[6] = f2bf(f1.z); v[7] = f2bf(f1.w);
            int eoff = row * 256 + ((c16 * 8) ^ ((row & 7) << 3));
            *(u16x8*)(As + eoff) = v;
        }
    }

    for (int ct = 0; ct < 6; ct++) {
        // stage B chunk: 128 cols x 256 k
        #pragma unroll
        for (int i = 0; i < 8; i++) {
            int chunk = i * 512 + tid;
            int row = chunk >> 5, c16 = chunk & 31;
            u16x8 v = *(const u16x8*)(wih_bf + ((size_t)(n * G_ + ct * 128 + row)) * I_ + c16 * 8);
            int eoff = row * 256 + ((c16 * 8) ^ ((row & 7) << 3));
            *(u16x8*)(Bs + eoff) = v;
        }
        __syncthreads();

        f4 acc[2][2];
        f4 zf = {0.f, 0.f, 0.f, 0.f};
        #pragma unroll
        for (int m = 0; m < 2; m++)
            #pragma unroll
            for (int nb2 = 0; nb2 < 2; nb2++) acc[m][nb2] = zf;

        int q16 = (lane >> 4) * 8;
        #pragma unroll
        for (int kt = 0; kt < 8; kt++) {
            bf8 a[2], bb[2];
            #pragma unroll
            for (int m = 0; m < 2; m++) {
                int ar = wr * 32 + m * 16 + (lane & 15);
                a[m] = *(const bf8*)(As + ar * 256 + ((kt * 32 + q16) ^ ((ar & 7) << 3)));
            }
            #pragma unroll
            for (int nb2 = 0; nb2 < 2; nb2++) {
                int br = wc * 32 + nb2 * 16 + (lane & 15);
                bb[nb2] = *(const bf8*)(Bs + br * 256 + ((kt * 32 + q16) ^ ((br & 7) << 3)));
            }
            #pragma unroll
            for (int m = 0; m < 2; m++)
                #pragma unroll
                for (int nb2 = 0; nb2 < 2; nb2++)
                    acc[m][nb2] = __builtin_amdgcn_mfma_f32_16x16x32_bf16(a[m], bb[nb2], acc[m][nb2], 0, 0, 0);
        }

        // epilogue: +bias, store bf16. D: col = lane&15, row = (lane>>4)*4 + r
        #pragma unroll
        for (int nb2 = 0; nb2 < 2; nb2++) {
            int col = wc * 32 + nb2 * 16 + (lane & 15);
            int g = ct * 128 + col;
            float bias = bias_f[n * G_ + g];
            #pragma unroll
            for (int m = 0; m < 2; m++) {
                #pragma unroll
                for (int r = 0; r < 4; r++) {
                    int trow = wr * 32 + m * 16 + (lane >> 4) * 4 + r;
                    size_t oidx = ((size_t)(b * N_ + n) * TC + trow) * G_ + g;
                    IH[oidx] = f2bf(acc[m][nb2][r] + bias);
                }
            }
        }
        __syncthreads();
    }
}

// ---------------- stage 2: sequential GRU scan over one T-chunk ----------------
// grid: 256 blocks = (n, 4-row group). 512 threads / 8 waves.
// wave w owns gate columns [w*96, w*96+96): 6 col-tiles x 8 k-tiles of whh in VGPRs.
__global__ __launch_bounds__(512, 2) void gru_scan(
        const unsigned char* __restrict__ wsr, unsigned char* ws,
        const float* __restrict__ bhh, float* __restrict__ out,
        int chunk, int t0) {
    const unsigned short* IH = (const unsigned short*)(wsr + OFF_IH);
    const unsigned short* whh_fr = (const unsigned short*)(wsr + OFF_WHH);
    float* h32ws = (float*)(ws + OFF_H32);

    __shared__ float hh_s[4 * 776];                     // hh per row, padded stride
    __shared__ float h32s[4 * 256];                     // fp32 h state
    __shared__ __align__(16) unsigned short hbf[4 * 272]; // bf16 h (stride 272 for banks)
    __shared__ float bhhn_s[256];

    int tid = threadIdx.x, lane = tid & 63, w = tid >> 6;
    int n = blockIdx.x & 15, rg = blockIdx.x >> 4;

    // register-resident whh fragments (coalesced: pre-shuffled layout)
    bf8 wf[6][8];
    #pragma unroll
    for (int c = 0; c < 6; c++)
        #pragma unroll
        for (int kt = 0; kt < 8; kt++)
            wf[c][kt] = *(const bf8*)(whh_fr + ((((size_t)n * 48 + (w * 6 + c)) * 8 + kt) * 64 + lane) * 8);

    if (tid < 256) bhhn_s[tid] = bhh[n * G_ + 512 + tid];

    // init / restore h state
    #pragma unroll
    for (int p = 0; p < 2; p++) {
        int uu = tid + p * 512;
        int row = uu >> 8, j = uu & 255;
        float hv = 0.f;
        if (chunk) hv = h32ws[((size_t)(rg * 4 + row) * N_ + n) * H_ + j];
        h32s[row * 256 + j] = hv;
        hbf[row * 272 + j] = f2bf(hv);
    }
    __syncthreads();

    int arow = lane & 15;
    bool av = arow < 4;
    int q16 = (lane >> 4) * 8;
    bf8 zb = {0, 0, 0, 0, 0, 0, 0, 0};
    f4 zf = {0.f, 0.f, 0.f, 0.f};

    #pragma unroll 1
    for (int t = 0; t < TC; t++) {
        // prefetch this step's IH (consumed after the MFMA phase)
        unsigned short pih[2][3];
        #pragma unroll
        for (int p = 0; p < 2; p++) {
            int uu = tid + p * 512;
            int row = uu >> 8, j = uu & 255;
            size_t base = ((size_t)((rg * 4 + row) * N_ + n) * TC + t) * G_ + j;
            pih[p][0] = IH[base];
            pih[p][1] = IH[base + 256];
            pih[p][2] = IH[base + 512];
        }

        // hh = h @ whh^T  (rows 0..3 real, 4..15 zero)
        f4 acc[6];
        #pragma unroll
        for (int c = 0; c < 6; c++) acc[c] = zf;
        #pragma unroll
        for (int kt = 0; kt < 8; kt++) {
            bf8 a = zb;
            if (av) a = *(const bf8*)(hbf + arow * 272 + kt * 32 + q16);
            #pragma unroll
            for (int c = 0; c < 6; c++)
                acc[c] = __builtin_amdgcn_mfma_f32_16x16x32_bf16(a, wf[c][kt], acc[c], 0, 0, 0);
        }
        // lanes 0..15 hold rows 0..3 (D: col=lane&15, row=reg)
        if (lane < 16) {
            #pragma unroll
            for (int c = 0; c < 6; c++) {
                int gc = (w * 6 + c) * 16 + lane;
                #pragma unroll
                for (int r = 0; r < 4; r++) hh_s[r * 776 + gc] = acc[c][r];
            }
        }
        __syncthreads();

        // gates + h update + output
        #pragma unroll
        for (int p = 0; p < 2; p++) {
            int uu = tid + p * 512;
            int row = uu >> 8, j = uu & 255;
            float hhr = hh_s[row * 776 + j];
            float hhz = hh_s[row * 776 + 256 + j];
            float hhn = hh_s[row * 776 + 512 + j];
            float xr = bf2f(pih[p][0]) + hhr;   // biases (bih+bhh) folded into IH
            float xz = bf2f(pih[p][1]) + hhz;
            float rr = 1.f / (1.f + __expf(-xr));
            float zz = 1.f / (1.f + __expf(-xz));
            float pre = bf2f(pih[p][2]) + rr * (hhn + bhhn_s[j]);
            float e2 = __expf(2.f * pre);
            float nv = 1.f - 2.f / (e2 + 1.f);  // tanh, inf-safe
            float hp = h32s[row * 256 + j];
            float hn = nv + zz * (hp - nv);     // (1-z)*n + z*h
            h32s[row * 256 + j] = hn;
            hbf[row * 272 + j] = f2bf(hn);
            out[((size_t)((rg * 4 + row) * N_ + n) * T_ + (t0 + t)) * H_ + j] = hn;
        }
        __syncthreads();
    }

    // persist h state for next chunk
    #pragma unroll
    for (int p = 0; p < 2; p++) {
        int uu = tid + p * 512;
        int row = uu >> 8, j = uu & 255;
        h32ws[((size_t)(rg * 4 + row) * N_ + n) * H_ + j] = h32s[row * 256 + j];
    }
}

extern "C" void kernel_launch(void* const* d_in, const int* in_sizes, int n_in,
                              void* d_out, int out_size, void* d_ws, size_t ws_size,
                              hipStream_t stream) {
    const float* x   = (const float*)d_in[0];
    const float* wih = (const float*)d_in[1];
    const float* whh = (const float*)d_in[2];
    const float* bih = (const float*)d_in[3];
    const float* bhh = (const float*)d_in[4];
    float* out = (float*)d_out;
    unsigned char* ws = (unsigned char*)d_ws;

    if (ws_size < WS_NEEDED) return;  // distinguishable: dur ~0 vs layout bug with normal dur

    prep_kernel<<<1024, 256, 0, stream>>>(wih, whh, bih, bhh, ws);
    for (int chunk = 0; chunk < 2; chunk++) {
        int t0 = chunk * TC;
        ih_gemm<<<dim3(1024), 512, 0, stream>>>(x, ws, ws, t0);
        gru_scan<<<dim3(256), 512, 0, stream>>>(ws, ws, bhh, out, chunk, t0);
    }
}

// Round 2
// 325.556 us; speedup vs baseline: 1.2378x; 1.2378x over previous
//
#include <hip/hip_runtime.h>
#include <stdint.h>

#define B_ 64
#define N_ 16
#define T_ 128
#define I_ 256
#define H_ 256
#define G_ 768   // 3*H
#define TC 64    // time chunk

typedef __attribute__((ext_vector_type(8))) short bf8;        // 8 bf16 in 4 VGPRs (MFMA frag)
typedef __attribute__((ext_vector_type(8))) unsigned short u16x8;
typedef __attribute__((ext_vector_type(4))) float f4;

static __device__ __forceinline__ unsigned short f2bf(float f) {
    uint32_t u = __builtin_bit_cast(uint32_t, f);
    u += 0x7fffu + ((u >> 16) & 1u);   // RNE
    return (unsigned short)(u >> 16);
}
static __device__ __forceinline__ float bf2f(unsigned short s) {
    return __builtin_bit_cast(float, ((uint32_t)s) << 16);
}
static __device__ __forceinline__ float sigm(float x) {
    return __builtin_amdgcn_rcpf(1.f + __expf(-x));
}

// ---- ws layout (bytes) ----
#define OFF_WIH   0ull
#define OFF_WHH   6291456ull
#define OFF_BIAS  12582912ull
#define OFF_H32   12632064ull
#define OFF_IH    13680640ull
#define WS_NEEDED (OFF_IH + 100663296ull)

// ---------------- stage 0: convert/shuffle weights ----------------
__global__ __launch_bounds__(256) void prep_kernel(
        const float* __restrict__ wih, const float* __restrict__ whh,
        const float* __restrict__ bih, const float* __restrict__ bhh,
        unsigned char* ws) {
    unsigned short* wih_bf = (unsigned short*)(ws + OFF_WIH);
    unsigned short* whh_fr = (unsigned short*)(ws + OFF_WHH);
    float* bias_f = (float*)(ws + OFF_BIAS);
    int gid = blockIdx.x * blockDim.x + threadIdx.x;
    int nthr = gridDim.x * blockDim.x;

    for (int o = gid; o < 393216; o += nthr) {
        const float* s = wih + (size_t)o * 8;
        u16x8 v;
        #pragma unroll
        for (int e = 0; e < 8; e++) v[e] = f2bf(s[e]);
        *(u16x8*)(wih_bf + (size_t)o * 8) = v;
    }
    // whh: gather into fragment order [n][ct(48)][kt(8)][lane(64)][e(8)]
    //   B-frag: col = ct*16 + (lane&15), k = kt*32 + (lane>>4)*8 + e
    for (int o = gid; o < 393216; o += nthr) {
        int lane = o & 63, kt = (o >> 6) & 7, ct = (o >> 9) % 48, n = o / 24576;
        int gcol = ct * 16 + (lane & 15);
        int k0 = kt * 32 + (lane >> 4) * 8;
        const float* s = whh + ((size_t)(n * G_ + gcol)) * H_ + k0;
        u16x8 v;
        #pragma unroll
        for (int e = 0; e < 8; e++) v[e] = f2bf(s[e]);
        *(u16x8*)(whh_fr + (size_t)o * 8) = v;
    }
    for (int o = gid; o < N_ * G_; o += nthr) {
        int g = o % G_;
        bias_f[o] = bih[o] + (g < 512 ? bhh[o] : 0.f);
    }
}

// ---------------- stage 1: IH = bf16( x @ wih^T + bias_f ) for one T-chunk ----------------
__global__ __launch_bounds__(512, 2) void ih_gemm(
        const float* __restrict__ x, const unsigned char* __restrict__ wsr,
        unsigned char* ws, int t0) {
    const unsigned short* wih_bf = (const unsigned short*)(wsr + OFF_WIH);
    const float* bias_f = (const float*)(wsr + OFF_BIAS);
    unsigned short* IH = (unsigned short*)(ws + OFF_IH);

    __shared__ __align__(16) unsigned short As[64 * 256];
    __shared__ __align__(16) unsigned short Bs[128 * 256];

    int tid = threadIdx.x;
    int lane = tid & 63, w = tid >> 6;
    int wr = w >> 2, wc = w & 3;
    int n = blockIdx.x >> 6, b = blockIdx.x & 63;

    {
        const float* xb = x + (((size_t)(b * N_ + n)) * T_ + t0) * I_;
        #pragma unroll
        for (int i = 0; i < 4; i++) {
            int chunk = i * 512 + tid;
            int row = chunk >> 5, c16 = chunk & 31;
            const float* s = xb + row * I_ + c16 * 8;
            float4 f0 = *(const float4*)s;
            float4 f1 = *(const float4*)(s + 4);
            u16x8 v;
            v[0] = f2bf(f0.x); v[1] = f2bf(f0.y); v[2] = f2bf(f0.z); v[3] = f2bf(f0.w);
            v[4] = f2bf(f1.x); v[5] = f2bf(f1.y); v[6] = f2bf(f1.z); v[7] = f2bf(f1.w);
            int eoff = row * 256 + ((c16 * 8) ^ ((row & 7) << 3));
            *(u16x8*)(As + eoff) = v;
        }
    }

    for (int ct = 0; ct < 6; ct++) {
        #pragma unroll
        for (int i = 0; i < 8; i++) {
            int chunk = i * 512 + tid;
            int row = chunk >> 5, c16 = chunk & 31;
            u16x8 v = *(const u16x8*)(wih_bf + ((size_t)(n * G_ + ct * 128 + row)) * I_ + c16 * 8);
            int eoff = row * 256 + ((c16 * 8) ^ ((row & 7) << 3));
            *(u16x8*)(Bs + eoff) = v;
        }
        __syncthreads();

        f4 acc[2][2];
        f4 zf = {0.f, 0.f, 0.f, 0.f};
        #pragma unroll
        for (int m = 0; m < 2; m++)
            #pragma unroll
            for (int nb2 = 0; nb2 < 2; nb2++) acc[m][nb2] = zf;

        int q16 = (lane >> 4) * 8;
        #pragma unroll
        for (int kt = 0; kt < 8; kt++) {
            bf8 a[2], bb[2];
            #pragma unroll
            for (int m = 0; m < 2; m++) {
                int ar = wr * 32 + m * 16 + (lane & 15);
                a[m] = *(const bf8*)(As + ar * 256 + ((kt * 32 + q16) ^ ((ar & 7) << 3)));
            }
            #pragma unroll
            for (int nb2 = 0; nb2 < 2; nb2++) {
                int br = wc * 32 + nb2 * 16 + (lane & 15);
                bb[nb2] = *(const bf8*)(Bs + br * 256 + ((kt * 32 + q16) ^ ((br & 7) << 3)));
            }
            #pragma unroll
            for (int m = 0; m < 2; m++)
                #pragma unroll
                for (int nb2 = 0; nb2 < 2; nb2++)
                    acc[m][nb2] = __builtin_amdgcn_mfma_f32_16x16x32_bf16(a[m], bb[nb2], acc[m][nb2], 0, 0, 0);
        }

        #pragma unroll
        for (int nb2 = 0; nb2 < 2; nb2++) {
            int col = wc * 32 + nb2 * 16 + (lane & 15);
            int g = ct * 128 + col;
            float bias = bias_f[n * G_ + g];
            #pragma unroll
            for (int m = 0; m < 2; m++) {
                #pragma unroll
                for (int r = 0; r < 4; r++) {
                    int trow = wr * 32 + m * 16 + (lane >> 4) * 4 + r;
                    size_t oidx = ((size_t)(b * N_ + n) * TC + trow) * G_ + g;
                    IH[oidx] = f2bf(acc[m][nb2][r] + bias);
                }
            }
        }
        __syncthreads();
    }
}

// ---------------- stage 2: sequential GRU scan, v2 ----------------
// 256 blocks = (n, 4-row group), 512 threads / 8 waves.
// Wave w owns H-cols [w*32, w*32+32) for ALL 3 gates: tiles ct = g*16 + w*2 + u.
// A rows replicated (row i = h[i>>2]) so D lane l reg0 = hh[l>>4][l&15] -> in-register gates.
// One barrier per step; h bf16 tile double-buffered in LDS; IH prefetched one full step ahead.
__global__ __launch_bounds__(512, 2) void gru_scan(
        const unsigned char* __restrict__ wsr, unsigned char* ws,
        const float* __restrict__ bhh, float* __restrict__ out,
        int chunk, int t0) {
    const unsigned short* IH = (const unsigned short*)(wsr + OFF_IH);
    const unsigned short* whh_fr = (const unsigned short*)(wsr + OFF_WHH);
    float* h32ws = (float*)(ws + OFF_H32);

    __shared__ __align__(16) unsigned short hbf[2][4][272];  // [buf][hrow][col], stride 272 for banks

    int tid = threadIdx.x, lane = tid & 63, w = tid >> 6;
    int n = blockIdx.x & 15, rg = blockIdx.x >> 4;

    int c16 = lane & 15;          // col-within-tile; also A-row index
    int q = lane >> 4;            // k-quad for A-frag; b-row for gates
    int hrow = c16 >> 2;          // replicated A source row
    int q16 = q * 8;
    int brow = rg * 4 + q;        // this lane's b-row

    // register-resident whh fragments: 6 tiles x 8 kt
    bf8 wf[3][2][8];
    #pragma unroll
    for (int g = 0; g < 3; g++)
        #pragma unroll
        for (int u = 0; u < 2; u++) {
            int ct = g * 16 + w * 2 + u;
            #pragma unroll
            for (int kt = 0; kt < 8; kt++)
                wf[g][u][kt] = *(const bf8*)(whh_fr + ((((size_t)n * 48 + ct) * 8 + kt) * 64 + lane) * 8);
        }

    int colb = w * 32 + c16;      // u=0 column; u=1 adds 16
    float bn0 = bhh[n * G_ + 512 + colb];
    float bn1 = bhh[n * G_ + 512 + colb + 16];
    float h0 = 0.f, h1 = 0.f;
    if (chunk) {
        const float* hp = h32ws + ((size_t)brow * N_ + n) * H_ + colb;
        h0 = hp[0]; h1 = hp[16];
    }
    hbf[0][q][colb] = f2bf(h0);
    hbf[0][q][colb + 16] = f2bf(h1);

    const unsigned short* ihp = IH + ((size_t)(brow * N_ + n) * TC) * G_ + colb;

    // prefetch t=0
    unsigned short c_r0 = ihp[0],   c_r1 = ihp[16];
    unsigned short c_z0 = ihp[256], c_z1 = ihp[272];
    unsigned short c_n0 = ihp[512], c_n1 = ihp[528];
    ihp += G_;

    f4 zf = {0.f, 0.f, 0.f, 0.f};
    __syncthreads();

    #pragma unroll 1
    for (int t = 0; t < TC; t++) {
        // prefetch t+1 (clamped re-read on last step)
        const unsigned short* pp = (t + 1 < TC) ? ihp : (ihp - G_);
        unsigned short n_r0 = pp[0],   n_r1 = pp[16];
        unsigned short n_z0 = pp[256], n_z1 = pp[272];
        unsigned short n_n0 = pp[512], n_n1 = pp[528];
        ihp += G_;

        // hh = h @ whh^T with replicated A rows
        const unsigned short* hb = &hbf[t & 1][0][0];
        f4 acc[3][2];
        #pragma unroll
        for (int g = 0; g < 3; g++)
            #pragma unroll
            for (int u = 0; u < 2; u++) acc[g][u] = zf;
        #pragma unroll
        for (int kt = 0; kt < 8; kt++) {
            bf8 a = *(const bf8*)(hb + hrow * 272 + kt * 32 + q16);
            #pragma unroll
            for (int g = 0; g < 3; g++)
                #pragma unroll
                for (int u = 0; u < 2; u++)
                    acc[g][u] = __builtin_amdgcn_mfma_f32_16x16x32_bf16(a, wf[g][u][kt], acc[g][u], 0, 0, 0);
        }

        // in-register gates: lane l handles (row l>>4, cols colb, colb+16)
        float xr0 = bf2f(c_r0) + acc[0][0][0];
        float xz0 = bf2f(c_z0) + acc[1][0][0];
        float rr0 = sigm(xr0), zz0 = sigm(xz0);
        float pre0 = bf2f(c_n0) + rr0 * (acc[2][0][0] + bn0);
        float e20 = __expf(2.f * pre0);
        float nv0 = 1.f - 2.f * __builtin_amdgcn_rcpf(e20 + 1.f);
        float hn0 = nv0 + zz0 * (h0 - nv0);

        float xr1 = bf2f(c_r1) + acc[0][1][0];
        float xz1 = bf2f(c_z1) + acc[1][1][0];
        float rr1 = sigm(xr1), zz1 = sigm(xz1);
        float pre1 = bf2f(c_n1) + rr1 * (acc[2][1][0] + bn1);
        float e21 = __expf(2.f * pre1);
        float nv1 = 1.f - 2.f * __builtin_amdgcn_rcpf(e21 + 1.f);
        float hn1 = nv1 + zz1 * (h1 - nv1);

        h0 = hn0; h1 = hn1;

        unsigned short* hw = &hbf[(t & 1) ^ 1][q][colb];
        hw[0] = f2bf(hn0);
        hw[16] = f2bf(hn1);

        float* op = out + ((size_t)(brow * N_ + n) * T_ + (t0 + t)) * H_ + colb;
        op[0] = hn0;
        op[16] = hn1;

        // rotate prefetch regs
        c_r0 = n_r0; c_r1 = n_r1;
        c_z0 = n_z0; c_z1 = n_z1;
        c_n0 = n_n0; c_n1 = n_n1;

        __syncthreads();
    }

    // persist h state for next chunk
    float* hp = h32ws + ((size_t)brow * N_ + n) * H_ + colb;
    hp[0] = h0;
    hp[16] = h1;
}

extern "C" void kernel_launch(void* const* d_in, const int* in_sizes, int n_in,
                              void* d_out, int out_size, void* d_ws, size_t ws_size,
                              hipStream_t stream) {
    const float* x   = (const float*)d_in[0];
    const float* wih = (const float*)d_in[1];
    const float* whh = (const float*)d_in[2];
    const float* bih = (const float*)d_in[3];
    const float* bhh = (const float*)d_in[4];
    float* out = (float*)d_out;
    unsigned char* ws = (unsigned char*)d_ws;

    if (ws_size < WS_NEEDED) return;

    prep_kernel<<<1024, 256, 0, stream>>>(wih, whh, bih, bhh, ws);
    for (int chunk = 0; chunk < 2; chunk++) {
        int t0 = chunk * TC;
        ih_gemm<<<dim3(1024), 512, 0, stream>>>(x, ws, ws, t0);
        gru_scan<<<dim3(256), 512, 0, stream>>>(ws, ws, bhh, out, chunk, t0);
    }
}

// Round 3
// 314.128 us; speedup vs baseline: 1.2828x; 1.0364x over previous
//
#include <hip/hip_runtime.h>
#include <stdint.h>

#define B_ 64
#define N_ 16
#define T_ 128
#define I_ 256
#define H_ 256
#define G_ 768   // 3*H
#define TC 64    // time chunk

typedef __attribute__((ext_vector_type(8))) short bf8;        // 8 bf16 in 4 VGPRs (MFMA frag)
typedef __attribute__((ext_vector_type(8))) unsigned short u16x8;
typedef __attribute__((ext_vector_type(4))) float f4;

static __device__ __forceinline__ unsigned short f2bf(float f) {
    uint32_t u = __builtin_bit_cast(uint32_t, f);
    u += 0x7fffu + ((u >> 16) & 1u);   // RNE
    return (unsigned short)(u >> 16);
}
static __device__ __forceinline__ float bf2f(unsigned short s) {
    return __builtin_bit_cast(float, ((uint32_t)s) << 16);
}
static __device__ __forceinline__ float sigm(float x) {
    return __builtin_amdgcn_rcpf(1.f + __expf(-x));
}

// ---- ws layout (bytes) ----
// wih_fr  : 16*48*8*64*8 ushort = 6291456  (MFMA B-fragment order, same scheme as whh)
// whh_fr  : 6291456
// bias_f  : 16*768 float                   (bih + bhh for r/z cols, bih only for n cols)
// h32ws   : 64*16*256 float                (carry h between T-chunks)
// IH      : 64*16*TC*768 ushort            (one T-chunk of input projection, bf16)
#define OFF_WIH   0ull
#define OFF_WHH   6291456ull
#define OFF_BIAS  12582912ull
#define OFF_H32   12632064ull
#define OFF_IH    13680640ull
#define WS_NEEDED (OFF_IH + 100663296ull)

// ---------------- stage 0: convert/shuffle weights ----------------
__global__ __launch_bounds__(256) void prep_kernel(
        const float* __restrict__ wih, const float* __restrict__ whh,
        const float* __restrict__ bih, const float* __restrict__ bhh,
        unsigned char* ws) {
    unsigned short* wih_fr = (unsigned short*)(ws + OFF_WIH);
    unsigned short* whh_fr = (unsigned short*)(ws + OFF_WHH);
    float* bias_f = (float*)(ws + OFF_BIAS);
    int gid = blockIdx.x * blockDim.x + threadIdx.x;
    int nthr = gridDim.x * blockDim.x;

    // both weights: gather into fragment order [n][ct(48)][kt(8)][lane(64)][e(8)]
    //   B-frag: col = ct*16 + (lane&15), k = kt*32 + (lane>>4)*8 + e
    for (int o = gid; o < 393216; o += nthr) {
        int lane = o & 63, kt = (o >> 6) & 7, ct = (o >> 9) % 48, n = o / 24576;
        int gcol = ct * 16 + (lane & 15);
        int k0 = kt * 32 + (lane >> 4) * 8;
        const float* s0 = wih + ((size_t)(n * G_ + gcol)) * I_ + k0;
        const float* s1 = whh + ((size_t)(n * G_ + gcol)) * H_ + k0;
        u16x8 v0, v1;
        #pragma unroll
        for (int e = 0; e < 8; e++) { v0[e] = f2bf(s0[e]); v1[e] = f2bf(s1[e]); }
        *(u16x8*)(wih_fr + (size_t)o * 8) = v0;
        *(u16x8*)(whh_fr + (size_t)o * 8) = v1;
    }
    for (int o = gid; o < N_ * G_; o += nthr) {
        int g = o % G_;
        bias_f[o] = bih[o] + (g < 512 ? bhh[o] : 0.f);
    }
}

// ---------------- stage 1: IH = bf16( x @ wih^T + bias_f ) for one T-chunk ----------------
// grid 1024 = (n,b); block 512 thr / 8 waves; tile 64 rows x 768 cols, K=256.
// A (x, fp32->bf16) staged once in LDS (32KB, swizzled). B fragments loaded straight
// from the frag-ordered ws to VGPRs (coalesced 1KB/instr), double-buffered over kt.
__global__ __launch_bounds__(512, 2) void ih_gemm(
        const float* __restrict__ x, const unsigned char* __restrict__ wsr,
        unsigned char* ws, int t0) {
    const unsigned short* wih_fr = (const unsigned short*)(wsr + OFF_WIH);
    const float* bias_f = (const float*)(wsr + OFF_BIAS);
    unsigned short* IH = (unsigned short*)(ws + OFF_IH);

    __shared__ __align__(16) unsigned short As[64 * 256];

    int tid = threadIdx.x, lane = tid & 63, w = tid >> 6;
    int n = blockIdx.x >> 6, b = blockIdx.x & 63;
    int c16 = lane & 15, q = lane >> 4, q16 = q * 8;

    // stage A: 64 rows x 256 k (fp32 -> bf16), swizzled
    {
        const float* xb = x + (((size_t)(b * N_ + n)) * T_ + t0) * I_;
        #pragma unroll
        for (int i = 0; i < 4; i++) {
            int chunk = i * 512 + tid;
            int row = chunk >> 5, kc = chunk & 31;
            const float* s = xb + row * I_ + kc * 8;
            float4 f0 = *(const float4*)s;
            float4 f1 = *(const float4*)(s + 4);
            u16x8 v;
            v[0] = f2bf(f0.x); v[1] = f2bf(f0.y); v[2] = f2bf(f0.z); v[3] = f2bf(f0.w);
            v[4] = f2bf(f1.x); v[5] = f2bf(f1.y); v[6] = f2bf(f1.z); v[7] = f2bf(f1.w);
            int eoff = row * 256 + ((kc * 8) ^ ((row & 7) << 3));
            *(u16x8*)(As + eoff) = v;
        }
    }
    __syncthreads();

    // wave w owns col-tiles ct = w*6 .. w*6+5
    const unsigned short* bptr = wih_fr + (((size_t)n * 48 + w * 6) * 8) * 64 * 8;

    f4 acc[4][6];
    f4 zf = {0.f, 0.f, 0.f, 0.f};
    #pragma unroll
    for (int rt = 0; rt < 4; rt++)
        #pragma unroll
        for (int c = 0; c < 6; c++) acc[rt][c] = zf;

    bf8 bc[6], bn[6];
    #pragma unroll
    for (int c = 0; c < 6; c++)
        bc[c] = *(const bf8*)(bptr + (((size_t)c * 8 + 0) * 64 + lane) * 8);

    #pragma unroll 1
    for (int kt = 0; kt < 8; kt++) {
        int ktn = (kt + 1) & 7;
        #pragma unroll
        for (int c = 0; c < 6; c++)
            bn[c] = *(const bf8*)(bptr + (((size_t)c * 8 + ktn) * 64 + lane) * 8);
        bf8 a[4];
        #pragma unroll
        for (int rt = 0; rt < 4; rt++) {
            int ar = rt * 16 + c16;
            a[rt] = *(const bf8*)(As + ar * 256 + ((kt * 32 + q16) ^ ((ar & 7) << 3)));
        }
        #pragma unroll
        for (int c = 0; c < 6; c++)
            #pragma unroll
            for (int rt = 0; rt < 4; rt++)
                acc[rt][c] = __builtin_amdgcn_mfma_f32_16x16x32_bf16(a[rt], bc[c], acc[rt][c], 0, 0, 0);
        #pragma unroll
        for (int c = 0; c < 6; c++) bc[c] = bn[c];
    }

    // epilogue: +bias, store bf16. D: col = lane&15, row = q*4 + r (within 16-tile)
    size_t obase = (size_t)(b * N_ + n) * TC;
    #pragma unroll
    for (int c = 0; c < 6; c++) {
        int g = (w * 6 + c) * 16 + c16;
        float bias = bias_f[n * G_ + g];
        #pragma unroll
        for (int rt = 0; rt < 4; rt++) {
            #pragma unroll
            for (int r = 0; r < 4; r++) {
                int trow = rt * 16 + q * 4 + r;
                IH[(obase + trow) * G_ + g] = f2bf(acc[rt][c][r] + bias);
            }
        }
    }
}

// ---------------- stage 2: sequential GRU scan (unchanged from R2) ----------------
__global__ __launch_bounds__(512, 2) void gru_scan(
        const unsigned char* __restrict__ wsr, unsigned char* ws,
        const float* __restrict__ bhh, float* __restrict__ out,
        int chunk, int t0) {
    const unsigned short* IH = (const unsigned short*)(wsr + OFF_IH);
    const unsigned short* whh_fr = (const unsigned short*)(wsr + OFF_WHH);
    float* h32ws = (float*)(ws + OFF_H32);

    __shared__ __align__(16) unsigned short hbf[2][4][272];

    int tid = threadIdx.x, lane = tid & 63, w = tid >> 6;
    int n = blockIdx.x & 15, rg = blockIdx.x >> 4;

    int c16 = lane & 15;
    int q = lane >> 4;
    int hrow = c16 >> 2;
    int q16 = q * 8;
    int brow = rg * 4 + q;

    bf8 wf[3][2][8];
    #pragma unroll
    for (int g = 0; g < 3; g++)
        #pragma unroll
        for (int u = 0; u < 2; u++) {
            int ct = g * 16 + w * 2 + u;
            #pragma unroll
            for (int kt = 0; kt < 8; kt++)
                wf[g][u][kt] = *(const bf8*)(whh_fr + ((((size_t)n * 48 + ct) * 8 + kt) * 64 + lane) * 8);
        }

    int colb = w * 32 + c16;
    float bn0 = bhh[n * G_ + 512 + colb];
    float bn1 = bhh[n * G_ + 512 + colb + 16];
    float h0 = 0.f, h1 = 0.f;
    if (chunk) {
        const float* hp = h32ws + ((size_t)brow * N_ + n) * H_ + colb;
        h0 = hp[0]; h1 = hp[16];
    }
    hbf[0][q][colb] = f2bf(h0);
    hbf[0][q][colb + 16] = f2bf(h1);

    const unsigned short* ihp = IH + ((size_t)(brow * N_ + n) * TC) * G_ + colb;

    unsigned short c_r0 = ihp[0],   c_r1 = ihp[16];
    unsigned short c_z0 = ihp[256], c_z1 = ihp[272];
    unsigned short c_n0 = ihp[512], c_n1 = ihp[528];
    ihp += G_;

    f4 zf = {0.f, 0.f, 0.f, 0.f};
    __syncthreads();

    #pragma unroll 1
    for (int t = 0; t < TC; t++) {
        const unsigned short* pp = (t + 1 < TC) ? ihp : (ihp - G_);
        unsigned short n_r0 = pp[0],   n_r1 = pp[16];
        unsigned short n_z0 = pp[256], n_z1 = pp[272];
        unsigned short n_n0 = pp[512], n_n1 = pp[528];
        ihp += G_;

        const unsigned short* hb = &hbf[t & 1][0][0];
        f4 acc[3][2];
        #pragma unroll
        for (int g = 0; g < 3; g++)
            #pragma unroll
            for (int u = 0; u < 2; u++) acc[g][u] = zf;
        #pragma unroll
        for (int kt = 0; kt < 8; kt++) {
            bf8 a = *(const bf8*)(hb + hrow * 272 + kt * 32 + q16);
            #pragma unroll
            for (int g = 0; g < 3; g++)
                #pragma unroll
                for (int u = 0; u < 2; u++)
                    acc[g][u] = __builtin_amdgcn_mfma_f32_16x16x32_bf16(a, wf[g][u][kt], acc[g][u], 0, 0, 0);
        }

        float xr0 = bf2f(c_r0) + acc[0][0][0];
        float xz0 = bf2f(c_z0) + acc[1][0][0];
        float rr0 = sigm(xr0), zz0 = sigm(xz0);
        float pre0 = bf2f(c_n0) + rr0 * (acc[2][0][0] + bn0);
        float e20 = __expf(2.f * pre0);
        float nv0 = 1.f - 2.f * __builtin_amdgcn_rcpf(e20 + 1.f);
        float hn0 = nv0 + zz0 * (h0 - nv0);

        float xr1 = bf2f(c_r1) + acc[0][1][0];
        float xz1 = bf2f(c_z1) + acc[1][1][0];
        float rr1 = sigm(xr1), zz1 = sigm(xz1);
        float pre1 = bf2f(c_n1) + rr1 * (acc[2][1][0] + bn1);
        float e21 = __expf(2.f * pre1);
        float nv1 = 1.f - 2.f * __builtin_amdgcn_rcpf(e21 + 1.f);
        float hn1 = nv1 + zz1 * (h1 - nv1);

        h0 = hn0; h1 = hn1;

        unsigned short* hw = &hbf[(t & 1) ^ 1][q][colb];
        hw[0] = f2bf(hn0);
        hw[16] = f2bf(hn1);

        float* op = out + ((size_t)(brow * N_ + n) * T_ + (t0 + t)) * H_ + colb;
        op[0] = hn0;
        op[16] = hn1;

        c_r0 = n_r0; c_r1 = n_r1;
        c_z0 = n_z0; c_z1 = n_z1;
        c_n0 = n_n0; c_n1 = n_n1;

        __syncthreads();
    }

    float* hp = h32ws + ((size_t)brow * N_ + n) * H_ + colb;
    hp[0] = h0;
    hp[16] = h1;
}

extern "C" void kernel_launch(void* const* d_in, const int* in_sizes, int n_in,
                              void* d_out, int out_size, void* d_ws, size_t ws_size,
                              hipStream_t stream) {
    const float* x   = (const float*)d_in[0];
    const float* wih = (const float*)d_in[1];
    const float* whh = (const float*)d_in[2];
    const float* bih = (const float*)d_in[3];
    const float* bhh = (const float*)d_in[4];
    float* out = (float*)d_out;
    unsigned char* ws = (unsigned char*)d_ws;

    if (ws_size < WS_NEEDED) return;

    prep_kernel<<<1024, 256, 0, stream>>>(wih, whh, bih, bhh, ws);
    for (int chunk = 0; chunk < 2; chunk++) {
        int t0 = chunk * TC;
        ih_gemm<<<dim3(1024), 512, 0, stream>>>(x, ws, ws, t0);
        gru_scan<<<dim3(256), 512, 0, stream>>>(ws, ws, bhh, out, chunk, t0);
    }
}

// Round 4
// 298.400 us; speedup vs baseline: 1.3504x; 1.0527x over previous
//
#include <hip/hip_runtime.h>
#include <stdint.h>

#define B_ 64
#define N_ 16
#define T_ 128
#define I_ 256
#define H_ 256
#define G_ 768   // 3*H
#define TC 64    // time chunk

typedef __attribute__((ext_vector_type(8))) short bf8;        // 8 bf16 in 4 VGPRs (MFMA frag)
typedef __attribute__((ext_vector_type(8))) unsigned short u16x8;
typedef __attribute__((ext_vector_type(4))) float f4;

static __device__ __forceinline__ unsigned short f2bf(float f) {
    uint32_t u = __builtin_bit_cast(uint32_t, f);
    u += 0x7fffu + ((u >> 16) & 1u);   // RNE
    return (unsigned short)(u >> 16);
}
static __device__ __forceinline__ float bf2f(unsigned short s) {
    return __builtin_bit_cast(float, ((uint32_t)s) << 16);
}
static __device__ __forceinline__ float sigm(float x) {
    return __builtin_amdgcn_rcpf(1.f + __expf(-x));
}

// ---- ws layout (bytes) ----
#define OFF_WIH   0ull
#define OFF_WHH   6291456ull
#define OFF_BIAS  12582912ull
#define OFF_H32   12632064ull
#define OFF_IH    13680640ull
#define WS_NEEDED (OFF_IH + 100663296ull)

// ---------------- stage 0: convert/shuffle weights ----------------
__global__ __launch_bounds__(256) void prep_kernel(
        const float* __restrict__ wih, const float* __restrict__ whh,
        const float* __restrict__ bih, const float* __restrict__ bhh,
        unsigned char* ws) {
    unsigned short* wih_fr = (unsigned short*)(ws + OFF_WIH);
    unsigned short* whh_fr = (unsigned short*)(ws + OFF_WHH);
    float* bias_f = (float*)(ws + OFF_BIAS);
    int gid = blockIdx.x * blockDim.x + threadIdx.x;
    int nthr = gridDim.x * blockDim.x;

    // fragment order [n][ct(48)][kt(8)][lane(64)][e(8)]
    //   B-frag: col = ct*16 + (lane&15), k = kt*32 + (lane>>4)*8 + e
    for (int o = gid; o < 393216; o += nthr) {
        int lane = o & 63, kt = (o >> 6) & 7, ct = (o >> 9) % 48, n = o / 24576;
        int gcol = ct * 16 + (lane & 15);
        int k0 = kt * 32 + (lane >> 4) * 8;
        const float* s0 = wih + ((size_t)(n * G_ + gcol)) * I_ + k0;
        const float* s1 = whh + ((size_t)(n * G_ + gcol)) * H_ + k0;
        u16x8 v0, v1;
        #pragma unroll
        for (int e = 0; e < 8; e++) { v0[e] = f2bf(s0[e]); v1[e] = f2bf(s1[e]); }
        *(u16x8*)(wih_fr + (size_t)o * 8) = v0;
        *(u16x8*)(whh_fr + (size_t)o * 8) = v1;
    }
    for (int o = gid; o < N_ * G_; o += nthr) {
        int g = o % G_;
        bias_f[o] = bih[o] + (g < 512 ? bhh[o] : 0.f);
    }
}

// ---------------- stage 1: IH = bf16( x @ wih^T + bias_f ) for one T-chunk ----------------
// grid 1024 = (n,b); block 1024 thr / 16 waves; tile 64 rows x 768 cols, K=256.
// Wave w owns 3 col-tiles (48 cols): acc[4][3]=48 AGPR, ~118 unified regs -> 4 waves/SIMD.
__global__ __launch_bounds__(1024, 1) void ih_gemm(
        const float* __restrict__ x, const unsigned char* __restrict__ wsr,
        unsigned char* ws, int t0) {
    const unsigned short* wih_fr = (const unsigned short*)(wsr + OFF_WIH);
    const float* bias_f = (const float*)(wsr + OFF_BIAS);
    unsigned short* IH = (unsigned short*)(ws + OFF_IH);

    __shared__ __align__(16) unsigned short As[64 * 256];

    int tid = threadIdx.x, lane = tid & 63, w = tid >> 6;
    int n = blockIdx.x >> 6, b = blockIdx.x & 63;
    int c16 = lane & 15, q = lane >> 4, q16 = q * 8;

    // stage A: 64 rows x 256 k (fp32 -> bf16), swizzled
    {
        const float* xb = x + (((size_t)(b * N_ + n)) * T_ + t0) * I_;
        #pragma unroll
        for (int i = 0; i < 2; i++) {
            int chunk = i * 1024 + tid;
            int row = chunk >> 5, kc = chunk & 31;
            const float* s = xb + row * I_ + kc * 8;
            float4 f0 = *(const float4*)s;
            float4 f1 = *(const float4*)(s + 4);
            u16x8 v;
            v[0] = f2bf(f0.x); v[1] = f2bf(f0.y); v[2] = f2bf(f0.z); v[3] = f2bf(f0.w);
            v[4] = f2bf(f1.x); v[5] = f2bf(f1.y); v[6] = f2bf(f1.z); v[7] = f2bf(f1.w);
            int eoff = row * 256 + ((kc * 8) ^ ((row & 7) << 3));
            *(u16x8*)(As + eoff) = v;
        }
    }
    __syncthreads();

    // wave w owns col-tiles ct = w*3 .. w*3+2
    const unsigned short* bptr = wih_fr + (((size_t)n * 48 + w * 3) * 8) * 64 * 8;

    f4 acc[4][3];
    f4 zf = {0.f, 0.f, 0.f, 0.f};
    #pragma unroll
    for (int rt = 0; rt < 4; rt++)
        #pragma unroll
        for (int c = 0; c < 3; c++) acc[rt][c] = zf;

    bf8 bc[3], bn[3];
    #pragma unroll
    for (int c = 0; c < 3; c++)
        bc[c] = *(const bf8*)(bptr + (((size_t)c * 8 + 0) * 64 + lane) * 8);

    #pragma unroll 1
    for (int kt = 0; kt < 8; kt++) {
        int ktn = (kt + 1) & 7;
        #pragma unroll
        for (int c = 0; c < 3; c++)
            bn[c] = *(const bf8*)(bptr + (((size_t)c * 8 + ktn) * 64 + lane) * 8);
        bf8 a[4];
        #pragma unroll
        for (int rt = 0; rt < 4; rt++) {
            int ar = rt * 16 + c16;
            a[rt] = *(const bf8*)(As + ar * 256 + ((kt * 32 + q16) ^ ((ar & 7) << 3)));
        }
        #pragma unroll
        for (int c = 0; c < 3; c++)
            #pragma unroll
            for (int rt = 0; rt < 4; rt++)
                acc[rt][c] = __builtin_amdgcn_mfma_f32_16x16x32_bf16(a[rt], bc[c], acc[rt][c], 0, 0, 0);
        #pragma unroll
        for (int c = 0; c < 3; c++) bc[c] = bn[c];
    }

    // epilogue: +bias, store bf16. D: col = lane&15, row = q*4 + r (within 16-tile)
    size_t obase = (size_t)(b * N_ + n) * TC;
    #pragma unroll
    for (int c = 0; c < 3; c++) {
        int g = (w * 3 + c) * 16 + c16;
        float bias = bias_f[n * G_ + g];
        #pragma unroll
        for (int rt = 0; rt < 4; rt++) {
            #pragma unroll
            for (int r = 0; r < 4; r++) {
                int trow = rt * 16 + q * 4 + r;
                IH[(obase + trow) * G_ + g] = f2bf(acc[rt][c][r] + bias);
            }
        }
    }
}

// ---------------- stage 2: sequential GRU scan (unchanged) ----------------
__global__ __launch_bounds__(512, 2) void gru_scan(
        const unsigned char* __restrict__ wsr, unsigned char* ws,
        const float* __restrict__ bhh, float* __restrict__ out,
        int chunk, int t0) {
    const unsigned short* IH = (const unsigned short*)(wsr + OFF_IH);
    const unsigned short* whh_fr = (const unsigned short*)(wsr + OFF_WHH);
    float* h32ws = (float*)(ws + OFF_H32);

    __shared__ __align__(16) unsigned short hbf[2][4][272];

    int tid = threadIdx.x, lane = tid & 63, w = tid >> 6;
    int n = blockIdx.x & 15, rg = blockIdx.x >> 4;

    int c16 = lane & 15;
    int q = lane >> 4;
    int hrow = c16 >> 2;
    int q16 = q * 8;
    int brow = rg * 4 + q;

    bf8 wf[3][2][8];
    #pragma unroll
    for (int g = 0; g < 3; g++)
        #pragma unroll
        for (int u = 0; u < 2; u++) {
            int ct = g * 16 + w * 2 + u;
            #pragma unroll
            for (int kt = 0; kt < 8; kt++)
                wf[g][u][kt] = *(const bf8*)(whh_fr + ((((size_t)n * 48 + ct) * 8 + kt) * 64 + lane) * 8);
        }

    int colb = w * 32 + c16;
    float bn0 = bhh[n * G_ + 512 + colb];
    float bn1 = bhh[n * G_ + 512 + colb + 16];
    float h0 = 0.f, h1 = 0.f;
    if (chunk) {
        const float* hp = h32ws + ((size_t)brow * N_ + n) * H_ + colb;
        h0 = hp[0]; h1 = hp[16];
    }
    hbf[0][q][colb] = f2bf(h0);
    hbf[0][q][colb + 16] = f2bf(h1);

    const unsigned short* ihp = IH + ((size_t)(brow * N_ + n) * TC) * G_ + colb;

    unsigned short c_r0 = ihp[0],   c_r1 = ihp[16];
    unsigned short c_z0 = ihp[256], c_z1 = ihp[272];
    unsigned short c_n0 = ihp[512], c_n1 = ihp[528];
    ihp += G_;

    f4 zf = {0.f, 0.f, 0.f, 0.f};
    __syncthreads();

    #pragma unroll 1
    for (int t = 0; t < TC; t++) {
        const unsigned short* pp = (t + 1 < TC) ? ihp : (ihp - G_);
        unsigned short n_r0 = pp[0],   n_r1 = pp[16];
        unsigned short n_z0 = pp[256], n_z1 = pp[272];
        unsigned short n_n0 = pp[512], n_n1 = pp[528];
        ihp += G_;

        const unsigned short* hb = &hbf[t & 1][0][0];
        f4 acc[3][2];
        #pragma unroll
        for (int g = 0; g < 3; g++)
            #pragma unroll
            for (int u = 0; u < 2; u++) acc[g][u] = zf;
        #pragma unroll
        for (int kt = 0; kt < 8; kt++) {
            bf8 a = *(const bf8*)(hb + hrow * 272 + kt * 32 + q16);
            #pragma unroll
            for (int g = 0; g < 3; g++)
                #pragma unroll
                for (int u = 0; u < 2; u++)
                    acc[g][u] = __builtin_amdgcn_mfma_f32_16x16x32_bf16(a, wf[g][u][kt], acc[g][u], 0, 0, 0);
        }

        float xr0 = bf2f(c_r0) + acc[0][0][0];
        float xz0 = bf2f(c_z0) + acc[1][0][0];
        float rr0 = sigm(xr0), zz0 = sigm(xz0);
        float pre0 = bf2f(c_n0) + rr0 * (acc[2][0][0] + bn0);
        float e20 = __expf(2.f * pre0);
        float nv0 = 1.f - 2.f * __builtin_amdgcn_rcpf(e20 + 1.f);
        float hn0 = nv0 + zz0 * (h0 - nv0);

        float xr1 = bf2f(c_r1) + acc[0][1][0];
        float xz1 = bf2f(c_z1) + acc[1][1][0];
        float rr1 = sigm(xr1), zz1 = sigm(xz1);
        float pre1 = bf2f(c_n1) + rr1 * (acc[2][1][0] + bn1);
        float e21 = __expf(2.f * pre1);
        float nv1 = 1.f - 2.f * __builtin_amdgcn_rcpf(e21 + 1.f);
        float hn1 = nv1 + zz1 * (h1 - nv1);

        h0 = hn0; h1 = hn1;

        unsigned short* hw = &hbf[(t & 1) ^ 1][q][colb];
        hw[0] = f2bf(hn0);
        hw[16] = f2bf(hn1);

        float* op = out + ((size_t)(brow * N_ + n) * T_ + (t0 + t)) * H_ + colb;
        op[0] = hn0;
        op[16] = hn1;

        c_r0 = n_r0; c_r1 = n_r1;
        c_z0 = n_z0; c_z1 = n_z1;
        c_n0 = n_n0; c_n1 = n_n1;

        __syncthreads();
    }

    float* hp = h32ws + ((size_t)brow * N_ + n) * H_ + colb;
    hp[0] = h0;
    hp[16] = h1;
}

extern "C" void kernel_launch(void* const* d_in, const int* in_sizes, int n_in,
                              void* d_out, int out_size, void* d_ws, size_t ws_size,
                              hipStream_t stream) {
    const float* x   = (const float*)d_in[0];
    const float* wih = (const float*)d_in[1];
    const float* whh = (const float*)d_in[2];
    const float* bih = (const float*)d_in[3];
    const float* bhh = (const float*)d_in[4];
    float* out = (float*)d_out;
    unsigned char* ws = (unsigned char*)d_ws;

    if (ws_size < WS_NEEDED) return;

    prep_kernel<<<1024, 256, 0, stream>>>(wih, whh, bih, bhh, ws);
    for (int chunk = 0; chunk < 2; chunk++) {
        int t0 = chunk * TC;
        ih_gemm<<<dim3(1024), 1024, 0, stream>>>(x, ws, ws, t0);
        gru_scan<<<dim3(256), 512, 0, stream>>>(ws, ws, bhh, out, chunk, t0);
    }
}